// Round 13
// baseline (1398.640 us; speedup 1.0000x reference)
//
#include <hip/hip_runtime.h>
#include <hip/hip_bf16.h>
#include <stdint.h>

constexpr int TK   = 4096;   // B*S tokens
constexpr int DIMC = 1024;
constexpr int DFFC = 4096;
constexpr int VOC  = 32000;
constexpr int NL   = 3;

typedef __attribute__((ext_vector_type(8))) short bf16x8;
typedef __attribute__((ext_vector_type(8))) _Float16 half8;
typedef __attribute__((ext_vector_type(4))) float f32x4;
using u16 = unsigned short;

__device__ __forceinline__ u16 f2bf(float f) {
  unsigned int u = __float_as_uint(f);
  u += 0x7FFF + ((u >> 16) & 1);           // RNE; inputs finite
  return (u16)(u >> 16);
}

__device__ __forceinline__ void split16(float v, u16& hi, u16& lo) {
  _Float16 a = (_Float16)v;
  _Float16 b = (_Float16)(v - (float)a);
  hi = __builtin_bit_cast(u16, a);
  lo = __builtin_bit_cast(u16, b);
}

__device__ __forceinline__ float gelu_f(float x) {
  float x3 = x * x * x;
  return 0.5f * x * (1.0f + tanhf(0.7978845608028654f * (x + 0.044715f * x3)));
}

// async global->LDS, 16B/lane; LDS dest = wave-uniform base (+lane*16 in HW)
__device__ __forceinline__ void gll16(const void* g, void* l) {
  __builtin_amdgcn_global_load_lds(
      (const __attribute__((address_space(1))) unsigned int*)g,
      (__attribute__((address_space(3))) unsigned int*)l, 16, 0, 0);
}

// ---------------- init ----------------
__global__ __launch_bounds__(256) void k_init(const int* __restrict__ x,
    const float* __restrict__ emb, float* __restrict__ h,
    int* __restrict__ surv, int* __restrict__ cnts) {
  const int t = blockIdx.x, tid = threadIdx.x;
  if (t == 0 && tid < 16) cnts[tid] = (tid == 12) ? TK : 0;
  if (tid == 0) surv[t] = t;
  const int tok = x[t];
  ((float4*)(h + (size_t)t * DIMC))[tid] =
      ((const float4*)(emb + (size_t)tok * DIMC))[tid];
}

// ---------------- layernorm -> 2 fp16 planes (x16 scale) ----------------
__global__ __launch_bounds__(256) void k_ln(const float* __restrict__ h,
    const int* __restrict__ surv, const int* __restrict__ pM,
    const float* __restrict__ g, const float* __restrict__ b,
    u16* __restrict__ hn1, u16* __restrict__ hn2) {
  const int bidx = blockIdx.x;
  if (bidx >= *pM) return;
  const int t = surv[bidx];
  const int tid = threadIdx.x;
  const int lane = tid & 63, wid = tid >> 6;
  __shared__ float sm[4];
  float4 v = ((const float4*)(h + (size_t)t * DIMC))[tid];
  float s = v.x + v.y + v.z + v.w;
#pragma unroll
  for (int o = 32; o; o >>= 1) s += __shfl_down(s, o);
  if (lane == 0) sm[wid] = s;
  __syncthreads();
  const float mean = (sm[0] + sm[1] + sm[2] + sm[3]) * (1.0f / DIMC);
  __syncthreads();
  float4 d;
  d.x = v.x - mean; d.y = v.y - mean; d.z = v.z - mean; d.w = v.w - mean;
  float q = d.x * d.x + d.y * d.y + d.z * d.z + d.w * d.w;
#pragma unroll
  for (int o = 32; o; o >>= 1) q += __shfl_down(q, o);
  if (lane == 0) sm[wid] = q;
  __syncthreads();
  const float var = (sm[0] + sm[1] + sm[2] + sm[3]) * (1.0f / DIMC);
  const float rstd = 1.0f / sqrtf(var + 1e-5f);
  float4 gg = ((const float4*)g)[tid];
  float4 bb = ((const float4*)b)[tid];
  float o4[4];
  o4[0] = (d.x * rstd * gg.x + bb.x) * 16.f;
  o4[1] = (d.y * rstd * gg.y + bb.y) * 16.f;
  o4[2] = (d.z * rstd * gg.z + bb.z) * 16.f;
  o4[3] = (d.w * rstd * gg.w + bb.w) * 16.f;
  ushort4 u1, u2;
  split16(o4[0], u1.x, u2.x); split16(o4[1], u1.y, u2.y);
  split16(o4[2], u1.z, u2.z); split16(o4[3], u1.w, u2.w);
  ((ushort4*)(hn1 + (size_t)bidx * DIMC))[tid] = u1;
  ((ushort4*)(hn2 + (size_t)bidx * DIMC))[tid] = u2;
}

// ---------------- ALL weight transposes + fp16 2-splits, one dispatch ----------------
// grid 6144 = 3 stages x {W1: 16kb x 64nb, W2: 64kb x 16nb}
__global__ __launch_bounds__(256) void k_splitw_all(
    const float* __restrict__ W1, const float* __restrict__ W2,
    u16* __restrict__ W1all, u16* __restrict__ W2all)
{
  int bid = blockIdx.x;
  const int s = bid >> 11; bid &= 2047;
  const int tens = bid >> 10; bid &= 1023;
  const float* W; int K, N; u16 *O1, *O2; int bk, bn;
  if (tens == 0) {
    W = W1 + (size_t)s * DIMC * DFFC; K = DIMC; N = DFFC;
    O1 = W1all + (size_t)s * 2 * DFFC * DIMC;
    O2 = O1 + (size_t)DFFC * DIMC;
    bk = (bid & 15) * 64; bn = (bid >> 4) * 64;
  } else {
    W = W2 + (size_t)s * DFFC * DIMC; K = DFFC; N = DIMC;
    O1 = W2all + (size_t)s * 2 * DIMC * DFFC;
    O2 = O1 + (size_t)DIMC * DFFC;
    bk = (bid >> 4) * 64; bn = (bid & 15) * 64;
  }
  __shared__ float t[64][65];
  const int lx = threadIdx.x & 63, ly = threadIdx.x >> 6;
#pragma unroll
  for (int i = 0; i < 64; i += 4)
    t[ly + i][lx] = W[(size_t)(bk + ly + i) * N + bn + lx];
  __syncthreads();
  const int n4 = threadIdx.x >> 4;
  const int kq = (threadIdx.x & 15) * 4;
#pragma unroll
  for (int j = 0; j < 4; ++j) {
    const int n = j * 16 + n4;
    ushort4 h1, h2;
    {
      float v0 = t[kq + 0][n] * 256.f, v1 = t[kq + 1][n] * 256.f;
      float v2 = t[kq + 2][n] * 256.f, v3 = t[kq + 3][n] * 256.f;
      split16(v0, h1.x, h2.x); split16(v1, h1.y, h2.y);
      split16(v2, h1.z, h2.z); split16(v3, h1.w, h2.w);
    }
    const size_t o = (size_t)(bn + n) * K + bk + kq;
    *(ushort4*)&O1[o] = h1;
    *(ushort4*)&O2[o] = h2;
  }
}

// ---------------- f32 -> bf16 bulk convert (Wout, once per call) ----------------
__global__ __launch_bounds__(256) void k_cvtb(const float* __restrict__ in,
    u16* __restrict__ o, int n4) {
  int i = blockIdx.x * blockDim.x + threadIdx.x;
  const int stride = gridDim.x * blockDim.x;
  for (; i < n4; i += stride) {
    float4 v = ((const float4*)in)[i];
    ushort4 u;
    u.x = f2bf(v.x); u.y = f2bf(v.y); u.z = f2bf(v.z); u.w = f2bf(v.w);
    ((ushort4*)o)[i] = u;
  }
}

// ============ gemm1: 256x256 tile, 8 waves (128x64), BK=32, counted-vmcnt dbuf 128KB ============
// C ~= (A1+A2)(B1+B2)^T 3-term;  act = split64(gelu(C/4096 + b1))
__global__ __launch_bounds__(512, 1) void k_mlp1(
    const u16* __restrict__ wsb,
    int offA, int pstrA,            // hn planes [TK][DIMC]
    int offB, int pstrB,            // W1t planes [DFFC][DIMC]
    const int* __restrict__ pM,
    const float* __restrict__ bias,
    u16* __restrict__ O1, u16* __restrict__ O2)
{
  const int x = blockIdx.x & 7, g = blockIdx.x >> 3;   // grid 256 = 8 x 32
  const int rb = g & 15;                               // rb-fastest
  const int cb = x * 2 + (g >> 4);                     // 2 cb per XCD (B L2-resident)
  const int M = *pM;
  if (rb * 256 >= M) return;
  const int n0 = cb * 256;

  __shared__ u16 S[2][32768];     // dbuf x [A1(16)|A2(16)|B1(16)|B2(16)] subtiles of 512u16
  const int tid = threadIdx.x, w = tid >> 6, l = tid & 63;
  const int lr16 = l & 15, hi = l >> 4;

  int goff[8];
#pragma unroll
  for (int q = 0; q < 8; ++q) {
    const int bi = w * 8 + q;
    const int side = bi >> 5;                  // 0=A, 1=B
    const int pl = (bi >> 4) & 1;
    const int j = bi & 15;
    const int row = (side ? n0 : rb * 256) + j * 16 + lr16;
    const int base = side ? (offB + pl * pstrB) : (offA + pl * pstrA);
    goff[q] = base + row * DIMC + hi * 8;
  }

  const int wr = w >> 2, wc = w & 3;           // 2M x 4N wave grid, wave tile 128x64
  f32x4 acc[8][4];
#pragma unroll
  for (int mi = 0; mi < 8; ++mi)
#pragma unroll
    for (int ni = 0; ni < 4; ++ni) acc[mi][ni] = (f32x4){0.f, 0.f, 0.f, 0.f};

  auto STAGE = [&](int buf, int kt) {
#pragma unroll
    for (int q = 0; q < 8; ++q)
      gll16(wsb + (size_t)(goff[q] + kt * 32), (void*)&S[buf][(w * 8 + q) * 512]);
  };

  STAGE(0, 0);
  STAGE(1, 1);
  const int NT = DIMC / 32;                    // 32
  for (int kt = 0; kt < NT; ++kt) {
    const int cur = kt & 1;
    if (kt + 1 < NT) asm volatile("s_waitcnt vmcnt(8)" ::: "memory");
    else             asm volatile("s_waitcnt vmcnt(0)" ::: "memory");
    __builtin_amdgcn_s_barrier();
    half8 b1v[4], b2v[4];
#pragma unroll
    for (int ni = 0; ni < 4; ++ni) {
      const int sub = (32 + wc * 4 + ni) * 512 + l * 8;
      b1v[ni] = *(const half8*)&S[cur][sub];
      b2v[ni] = *(const half8*)&S[cur][sub + 8192];
    }
#pragma unroll
    for (int mh = 0; mh < 2; ++mh) {
      half8 a1v[4], a2v[4];
#pragma unroll
      for (int i = 0; i < 4; ++i) {
        const int sub = (wr * 8 + mh * 4 + i) * 512 + l * 8;
        a1v[i] = *(const half8*)&S[cur][sub];
        a2v[i] = *(const half8*)&S[cur][sub + 8192];
      }
      __builtin_amdgcn_s_setprio(1);
#pragma unroll
      for (int i = 0; i < 4; ++i)
#pragma unroll
        for (int ni = 0; ni < 4; ++ni) {
          f32x4 c = acc[mh * 4 + i][ni];
          c = __builtin_amdgcn_mfma_f32_16x16x32_f16(a2v[i], b1v[ni], c, 0, 0, 0);
          c = __builtin_amdgcn_mfma_f32_16x16x32_f16(a1v[i], b2v[ni], c, 0, 0, 0);
          c = __builtin_amdgcn_mfma_f32_16x16x32_f16(a1v[i], b1v[ni], c, 0, 0, 0);
          acc[mh * 4 + i][ni] = c;
        }
      __builtin_amdgcn_s_setprio(0);
    }
    asm volatile("s_waitcnt lgkmcnt(0)" ::: "memory");
    __builtin_amdgcn_s_barrier();
    if (kt + 2 < NT) STAGE(cur, kt + 2);
  }

#pragma unroll
  for (int mi = 0; mi < 8; ++mi)
#pragma unroll
    for (int ni = 0; ni < 4; ++ni) {
      const int n = n0 + wc * 64 + ni * 16 + lr16;
#pragma unroll
      for (int r = 0; r < 4; ++r) {
        const int m = rb * 256 + wr * 128 + mi * 16 + hi * 4 + r;
        float v = gelu_f(acc[mi][ni][r] * (1.f / 4096.f) + bias[n]) * 64.f;
        u16 h1, h2; split16(v, h1, h2);
        O1[(size_t)m * DFFC + n] = h1;
        O2[(size_t)m * DFFC + n] = h2;
      }
    }
}

// ============ gemm2: 256x128 tile, split-K2, 8 waves (64x64), BK=32, 3-ring 144KB ============
// counted-vmcnt (12/6/0 ladder).  PO[z-slab] = C/16384
__global__ __launch_bounds__(512, 1) void k_mlp2(
    const u16* __restrict__ wsb,
    int offA, int pstrA,            // act planes [TK][DFFC]
    int offB, int pstrB,            // W2t planes [DIMC][DFFC]
    const int* __restrict__ pM,
    float* __restrict__ PO)
{
  const int x = blockIdx.x & 7, g = blockIdx.x >> 3;   // grid 256 = 8 x 32
  const int rb = g & 15;
  const int cz = x * 2 + (g >> 4);                     // 0..15
  const int cb = cz & 7, z = cz >> 3;
  const int M = *pM;
  if (rb * 256 >= M) return;
  const int n0 = cb * 128;
  const int kz = z * 2048;

  __shared__ u16 S[3][24576];     // 3-ring x [A1(16)|A2(16)|B1(8)|B2(8)] subtiles of 512u16
  const int tid = threadIdx.x, w = tid >> 6, l = tid & 63;
  const int lr16 = l & 15, hi = l >> 4;

  int goff[6];
#pragma unroll
  for (int q = 0; q < 6; ++q) {
    const int bi = w * 6 + q;
    int base, row;
    if (bi < 32) {
      const int pl = bi >> 4, j = bi & 15;
      base = offA + pl * pstrA;
      row = rb * 256 + j * 16 + lr16;
    } else {
      const int bb = bi - 32, pl = bb >> 3, j = bb & 7;
      base = offB + pl * pstrB;
      row = n0 + j * 16 + lr16;
    }
    goff[q] = base + row * DFFC + kz + hi * 8;
  }

  const int wr = w >> 1, wc = w & 1;           // 4M x 2N wave grid, wave tile 64x64
  f32x4 acc[4][4];
#pragma unroll
  for (int mi = 0; mi < 4; ++mi)
#pragma unroll
    for (int ni = 0; ni < 4; ++ni) acc[mi][ni] = (f32x4){0.f, 0.f, 0.f, 0.f};

  auto STAGE = [&](int buf, int kt) {
#pragma unroll
    for (int q = 0; q < 6; ++q)
      gll16(wsb + (size_t)(goff[q] + kt * 32), (void*)&S[buf][(w * 6 + q) * 512]);
  };

  STAGE(0, 0);
  STAGE(1, 1);
  STAGE(2, 2);
  const int NT = 2048 / 32;                    // 64
  int cur = 0;
  for (int kt = 0; kt < NT; ++kt) {
    if (kt + 2 < NT)      asm volatile("s_waitcnt vmcnt(12)" ::: "memory");
    else if (kt + 1 < NT) asm volatile("s_waitcnt vmcnt(6)" ::: "memory");
    else                  asm volatile("s_waitcnt vmcnt(0)" ::: "memory");
    __builtin_amdgcn_s_barrier();
    half8 a1v[4], a2v[4], b1v[4], b2v[4];
#pragma unroll
    for (int mi = 0; mi < 4; ++mi) {
      const int sub = (wr * 4 + mi) * 512 + l * 8;
      a1v[mi] = *(const half8*)&S[cur][sub];
      a2v[mi] = *(const half8*)&S[cur][sub + 8192];
    }
#pragma unroll
    for (int ni = 0; ni < 4; ++ni) {
      const int sub = (32 + wc * 4 + ni) * 512 + l * 8;
      b1v[ni] = *(const half8*)&S[cur][sub];
      b2v[ni] = *(const half8*)&S[cur][sub + 4096];
    }
    __builtin_amdgcn_s_setprio(1);
#pragma unroll
    for (int mi = 0; mi < 4; ++mi)
#pragma unroll
      for (int ni = 0; ni < 4; ++ni) {
        f32x4 c = acc[mi][ni];
        c = __builtin_amdgcn_mfma_f32_16x16x32_f16(a2v[mi], b1v[ni], c, 0, 0, 0);
        c = __builtin_amdgcn_mfma_f32_16x16x32_f16(a1v[mi], b2v[ni], c, 0, 0, 0);
        c = __builtin_amdgcn_mfma_f32_16x16x32_f16(a1v[mi], b1v[ni], c, 0, 0, 0);
        acc[mi][ni] = c;
      }
    __builtin_amdgcn_s_setprio(0);
    asm volatile("s_waitcnt lgkmcnt(0)" ::: "memory");
    __builtin_amdgcn_s_barrier();
    if (kt + 3 < NT) STAGE(cur, kt + 3);       // refill the slot just consumed
    cur = (cur == 2) ? 0 : cur + 1;
  }

#pragma unroll
  for (int mi = 0; mi < 4; ++mi)
#pragma unroll
    for (int ni = 0; ni < 4; ++ni) {
      const int n = n0 + wc * 64 + ni * 16 + lr16;
#pragma unroll
      for (int r = 0; r < 4; ++r) {
        const int m = rb * 256 + wr * 64 + mi * 16 + hi * 4 + r;
        PO[(size_t)(z * TK + m) * DIMC + n] = acc[mi][ni][r] * (1.f / 16384.f);
      }
    }
}

// ---------------- decide: o = h + p0 + p1 + b2; cos; route token ----------------
__global__ __launch_bounds__(256) void k_decide(
    float* __restrict__ h, const float* __restrict__ p,
    const float* __restrict__ bias,
    const int* __restrict__ surv_in, int* __restrict__ surv_out,
    const int* __restrict__ pM, int* __restrict__ cnts,
    int* __restrict__ exit_idx, u16* __restrict__ hexit,
    int stage)
{
  const int bidx = blockIdx.x;
  if (bidx >= *pM) return;
  const int t = surv_in[bidx];
  const int tid = threadIdx.x;
  const int lane = tid & 63, wid = tid >> 6;
  __shared__ float sm[12];
  __shared__ int sif[2];
  float4 a  = ((const float4*)(h + (size_t)t * DIMC))[tid];
  float4 p0 = ((const float4*)(p + (size_t)bidx * DIMC))[tid];
  float4 p1 = ((const float4*)(p + (size_t)(TK + bidx) * DIMC))[tid];
  float4 bb = ((const float4*)bias)[tid];
  float4 o;
  o.x = a.x + p0.x + p1.x + bb.x;
  o.y = a.y + p0.y + p1.y + bb.y;
  o.z = a.z + p0.z + p1.z + bb.z;
  o.w = a.w + p0.w + p1.w + bb.w;
  float hh = a.x * a.x + a.y * a.y + a.z * a.z + a.w * a.w;
  float ho = a.x * o.x + a.y * o.y + a.z * o.z + a.w * o.w;
  float oo = o.x * o.x + o.y * o.y + o.z * o.z + o.w * o.w;
#pragma unroll
  for (int off = 32; off; off >>= 1) {
    hh += __shfl_down(hh, off);
    ho += __shfl_down(ho, off);
    oo += __shfl_down(oo, off);
  }
  if (lane == 0) { sm[wid] = hh; sm[4 + wid] = ho; sm[8 + wid] = oo; }
  __syncthreads();
  if (tid == 0) {
    int take;
    if (stage == NL - 1) take = 1;
    else {
      const float HH = sm[0] + sm[1] + sm[2] + sm[3];
      const float HO = sm[4] + sm[5] + sm[6] + sm[7];
      const float OO = sm[8] + sm[9] + sm[10] + sm[11];
      const float cosv = HO / (sqrtf(HH) * sqrtf(OO) + 1e-8f);
      take = (cosv >= 0.98f) ? 1 : 0;
    }
    int pos;
    if (take) {
      pos = atomicAdd(&cnts[stage], 1);
      exit_idx[pos] = t;
    } else {
      pos = atomicAdd(&cnts[4 + stage], 1);
      surv_out[pos] = t;
    }
    sif[0] = take; sif[1] = pos;
  }
  __syncthreads();
  if (sif[0]) {
    u16* dst = hexit + (size_t)sif[1] * DIMC;
    ushort4 u;
    u.x = f2bf(o.x); u.y = f2bf(o.y); u.z = f2bf(o.z); u.w = f2bf(o.w);
    ((ushort4*)dst)[tid] = u;
  } else {
    ((float4*)(h + (size_t)t * DIMC))[tid] = o;
  }
}

// ============ logits: bf16, 256x128 tile, BK=32, 3-ring 72KB, 8 waves, 2 blk/CU ============
// counted-vmcnt (6/3/0 ladder), rb-fastest XCD-partitioned swizzle.
__global__ __launch_bounds__(512, 4) void k_logits(
    const u16* __restrict__ wsb, int offA, int offB,
    const int* __restrict__ pcnt,
    const int* __restrict__ exit_idx,
    float* __restrict__ out)
{
  const int x = blockIdx.x & 7, g = blockIdx.x >> 3;   // grid 4096 = 8 x 512
  const int rb = g & 15;
  const int cb = x * 32 + (g >> 4);                    // 0..255
  if (cb >= VOC / 128) return;                         // 250 real cb
  const int cnt = *pcnt;
  if (rb * 256 >= cnt) return;
  const int n0 = cb * 128;

  __shared__ u16 S[3][12288];          // 3-ring x [A(16 subtiles) | B(8 subtiles)] x 512u16
  const int tid = threadIdx.x, w = tid >> 6, l = tid & 63;
  const int lr16 = l & 15, hi = l >> 4;

  int goff[3], loff[3];
#pragma unroll
  for (int q = 0; q < 3; ++q) {
    const int bi = w * 3 + q;          // 24 subtiles: A 0..15, B 16..23
    if (bi < 16) {
      goff[q] = offA + (rb * 256 + bi * 16 + lr16) * DIMC + hi * 8;
      loff[q] = bi * 512;
    } else {
      const int j = bi - 16;
      goff[q] = offB + (n0 + j * 16 + lr16) * DIMC + hi * 8;
      loff[q] = 8192 + j * 512;
    }
  }

  const int wr = w >> 1, wc = w & 1;   // 4M x 2N wave grid, wave tile 64x64
  f32x4 acc[4][4];
#pragma unroll
  for (int mi = 0; mi < 4; ++mi)
#pragma unroll
    for (int ni = 0; ni < 4; ++ni) acc[mi][ni] = (f32x4){0.f, 0.f, 0.f, 0.f};

  auto STAGE = [&](int buf, int kt) {
#pragma unroll
    for (int q = 0; q < 3; ++q)
      gll16(wsb + (size_t)(goff[q] + kt * 32), (void*)&S[buf][loff[q]]);
  };

  STAGE(0, 0);
  STAGE(1, 1);
  STAGE(2, 2);
  const int NT = DIMC / 32;            // 32
  int cur = 0;
  for (int kt = 0; kt < NT; ++kt) {
    if (kt + 2 < NT)      asm volatile("s_waitcnt vmcnt(6)" ::: "memory");
    else if (kt + 1 < NT) asm volatile("s_waitcnt vmcnt(3)" ::: "memory");
    else                  asm volatile("s_waitcnt vmcnt(0)" ::: "memory");
    __builtin_amdgcn_s_barrier();
    bf16x8 aF[4], bF[4];
#pragma unroll
    for (int mi = 0; mi < 4; ++mi)
      aF[mi] = *(const bf16x8*)&S[cur][(wr * 4 + mi) * 512 + l * 8];
#pragma unroll
    for (int ni = 0; ni < 4; ++ni)
      bF[ni] = *(const bf16x8*)&S[cur][8192 + (wc * 4 + ni) * 512 + l * 8];
    __builtin_amdgcn_s_setprio(1);
#pragma unroll
    for (int mi = 0; mi < 4; ++mi)
#pragma unroll
      for (int ni = 0; ni < 4; ++ni)
        acc[mi][ni] = __builtin_amdgcn_mfma_f32_16x16x32_bf16(aF[mi], bF[ni], acc[mi][ni], 0, 0, 0);
    __builtin_amdgcn_s_setprio(0);
    asm volatile("s_waitcnt lgkmcnt(0)" ::: "memory");
    __builtin_amdgcn_s_barrier();
    if (kt + 3 < NT) STAGE(cur, kt + 3);       // refill the slot just consumed
    cur = (cur == 2) ? 0 : cur + 1;
  }

  const int mvalid = cnt - rb * 256;
#pragma unroll
  for (int mi = 0; mi < 4; ++mi)
#pragma unroll
    for (int r = 0; r < 4; ++r) {
      const int mrow = wr * 64 + mi * 16 + hi * 4 + r;
      if (mrow < mvalid) {
        const int tok = exit_idx[rb * 256 + mrow];
        float* orow = out + (size_t)tok * VOC + n0 + wc * 64 + lr16;
#pragma unroll
        for (int ni = 0; ni < 4; ++ni)
          __builtin_nontemporal_store(acc[mi][ni][r], &orow[ni * 16]);
      }
    }
}

// ---------------- host ----------------
extern "C" void kernel_launch(void* const* d_in, const int* in_sizes, int n_in,
                              void* d_out, int out_size, void* d_ws, size_t ws_size,
                              hipStream_t stream)
{
  const int*   x    = (const int*)d_in[0];
  const float* emb  = (const float*)d_in[1];
  const float* ln_g = (const float*)d_in[2];
  const float* ln_b = (const float*)d_in[3];
  const float* W1   = (const float*)d_in[4];
  const float* b1   = (const float*)d_in[5];
  const float* W2   = (const float*)d_in[6];
  const float* b2   = (const float*)d_in[7];
  const float* Wout = (const float*)d_in[8];
  float* out = (float*)d_out;

  char* p = (char*)d_ws;
  size_t off = 0;
  auto alloc = [&](size_t bytes) -> void* {
    void* r = p + off;
    off += (bytes + 255) & ~(size_t)255;
    return r;
  };
  u16* wsb = (u16*)d_ws;
  float* h    = (float*)alloc((size_t)TK * DIMC * 4);
  float* pbuf = (float*)alloc((size_t)2 * TK * DIMC * 4);   // gemm2 partials; hn planes alias
  u16* hn1 = (u16*)pbuf;
  u16* hn2 = hn1 + (size_t)TK * DIMC;
  u16* act1 = (u16*)alloc((size_t)2 * TK * DFFC * 2);       // act1 | act2 contiguous
  u16* act2 = act1 + (size_t)TK * DFFC;
  u16* Woutb = (u16*)alloc((size_t)VOC * DIMC * 2);
  u16* W1all = (u16*)alloc((size_t)NL * 2 * DFFC * DIMC * 2);  // 3 stages x 2 planes
  u16* W2all = (u16*)alloc((size_t)NL * 2 * DIMC * DFFC * 2);
  u16* hexit = (u16*)alloc((size_t)TK * DIMC * 2);
  int* exit_idx = (int*)alloc((size_t)TK * 4);
  int* surv_a   = (int*)alloc((size_t)TK * 4);
  int* surv_b   = (int*)alloc((size_t)TK * 4);
  int* cnts     = (int*)alloc(64 * 4);
  // cnts[0..2]=exit counts; cnts[4..6]=survivor counts; cnts[12]=TK

  const int offHn  = (int)(hn1  - wsb);
  const int offAct = (int)(act1 - wsb);
  const int offWob = (int)(Woutb- wsb);
  const int offW1a = (int)(W1all- wsb);
  const int offW2a = (int)(W2all- wsb);
  const int offHex = (int)(hexit- wsb);
  const int pstrHn  = TK * DIMC;
  const int pstrAct = TK * DFFC;
  const int pstrW   = DFFC * DIMC;

  k_init<<<TK, 256, 0, stream>>>(x, emb, h, surv_a, cnts);
  k_cvtb<<<2048, 256, 0, stream>>>(Wout, Woutb, VOC * DIMC / 4);
  k_splitw_all<<<6144, 256, 0, stream>>>(W1, W2, W1all, W2all);
  int* surv_in  = surv_a;
  int* surv_out = surv_b;
  for (int i = 0; i < NL; ++i) {
    const int* pM = (i == 0) ? (cnts + 12) : (cnts + 4 + (i - 1));
    k_ln<<<TK, 256, 0, stream>>>(h, surv_in, pM, ln_g + i * DIMC, ln_b + i * DIMC, hn1, hn2);
    // gemm1: grid 256 = 8 XCD x (16 rb x 2 cbl)
    k_mlp1<<<256, 512, 0, stream>>>(
        wsb, offHn, pstrHn, offW1a + i * 2 * pstrW, pstrW,
        pM, b1 + (size_t)i * DFFC, act1, act2);
    // gemm2: grid 256 = 8 XCD x (16 rb x 2 cz), split-K2
    k_mlp2<<<256, 512, 0, stream>>>(
        wsb, offAct, pstrAct, offW2a + i * 2 * pstrW, pstrW, pM, pbuf);
    k_decide<<<TK, 256, 0, stream>>>(h, pbuf, b2 + (size_t)i * DIMC,
        surv_in, surv_out, pM, cnts, exit_idx, hexit, i);
    // logits: grid 4096 = 8 XCD x (16 rb x 32 cbl), cb>=250 idle
    k_logits<<<4096, 512, 0, stream>>>(wsb, offHex, offWob, cnts + i, exit_idx, out);
    int* tmp = surv_in; surv_in = surv_out; surv_out = tmp;
  }
}

// Round 14
// 1368.338 us; speedup vs baseline: 1.0221x; 1.0221x over previous
//
#include <hip/hip_runtime.h>
#include <hip/hip_bf16.h>
#include <stdint.h>

constexpr int TK   = 4096;   // B*S tokens
constexpr int DIMC = 1024;
constexpr int DFFC = 4096;
constexpr int VOC  = 32000;
constexpr int NL   = 3;

typedef __attribute__((ext_vector_type(8))) short bf16x8;
typedef __attribute__((ext_vector_type(8))) _Float16 half8;
typedef __attribute__((ext_vector_type(4))) float f32x4;
using u16 = unsigned short;

__device__ __forceinline__ u16 f2bf(float f) {
  unsigned int u = __float_as_uint(f);
  u += 0x7FFF + ((u >> 16) & 1);           // RNE; inputs finite
  return (u16)(u >> 16);
}

__device__ __forceinline__ void split16(float v, u16& hi, u16& lo) {
  _Float16 a = (_Float16)v;
  _Float16 b = (_Float16)(v - (float)a);
  hi = __builtin_bit_cast(u16, a);
  lo = __builtin_bit_cast(u16, b);
}

__device__ __forceinline__ float gelu_f(float x) {
  float x3 = x * x * x;
  return 0.5f * x * (1.0f + tanhf(0.7978845608028654f * (x + 0.044715f * x3)));
}

// async global->LDS, 16B/lane; LDS dest = wave-uniform base (+lane*16 in HW)
__device__ __forceinline__ void gll16(const void* g, void* l) {
  __builtin_amdgcn_global_load_lds(
      (const __attribute__((address_space(1))) unsigned int*)g,
      (__attribute__((address_space(3))) unsigned int*)l, 16, 0, 0);
}

// ---------------- init: gather emb + stage-0 LN -> hn planes ----------------
__global__ __launch_bounds__(256) void k_init(const int* __restrict__ x,
    const float* __restrict__ emb,
    const float* __restrict__ g, const float* __restrict__ b,
    float* __restrict__ h, u16* __restrict__ hn1, u16* __restrict__ hn2,
    int* __restrict__ surv, int* __restrict__ cnts) {
  const int t = blockIdx.x, tid = threadIdx.x;
  if (t == 0 && tid < 16) cnts[tid] = (tid == 12) ? TK : 0;
  if (tid == 0) surv[t] = t;
  const int tok = x[t];
  const int lane = tid & 63, wid = tid >> 6;
  __shared__ float sm[4];
  float4 v = ((const float4*)(emb + (size_t)tok * DIMC))[tid];
  ((float4*)(h + (size_t)t * DIMC))[tid] = v;
  float s = v.x + v.y + v.z + v.w;
#pragma unroll
  for (int o = 32; o; o >>= 1) s += __shfl_down(s, o);
  if (lane == 0) sm[wid] = s;
  __syncthreads();
  const float mean = (sm[0] + sm[1] + sm[2] + sm[3]) * (1.0f / DIMC);
  __syncthreads();
  float4 d;
  d.x = v.x - mean; d.y = v.y - mean; d.z = v.z - mean; d.w = v.w - mean;
  float q = d.x * d.x + d.y * d.y + d.z * d.z + d.w * d.w;
#pragma unroll
  for (int o = 32; o; o >>= 1) q += __shfl_down(q, o);
  if (lane == 0) sm[wid] = q;
  __syncthreads();
  const float var = (sm[0] + sm[1] + sm[2] + sm[3]) * (1.0f / DIMC);
  const float rstd = 1.0f / sqrtf(var + 1e-5f);
  float4 gg = ((const float4*)g)[tid];
  float4 bb = ((const float4*)b)[tid];
  float o4[4];
  o4[0] = (d.x * rstd * gg.x + bb.x) * 16.f;
  o4[1] = (d.y * rstd * gg.y + bb.y) * 16.f;
  o4[2] = (d.z * rstd * gg.z + bb.z) * 16.f;
  o4[3] = (d.w * rstd * gg.w + bb.w) * 16.f;
  ushort4 u1, u2;
  split16(o4[0], u1.x, u2.x); split16(o4[1], u1.y, u2.y);
  split16(o4[2], u1.z, u2.z); split16(o4[3], u1.w, u2.w);
  ((ushort4*)(hn1 + (size_t)t * DIMC))[tid] = u1;
  ((ushort4*)(hn2 + (size_t)t * DIMC))[tid] = u2;
}

// ---------------- prep: ALL weight transposes/splits + Wout->bf16, one dispatch ----------------
// grid 8192: [0,6144) = splitw (3 stages x {W1: 1024 blk, W2: 1024 blk}), [6144,8192) = cvtb
__global__ __launch_bounds__(256) void k_prep(
    const float* __restrict__ W1, const float* __restrict__ W2,
    u16* __restrict__ W1all, u16* __restrict__ W2all,
    const float* __restrict__ Wout, u16* __restrict__ Woutb)
{
  int bid = blockIdx.x;
  if (bid >= 6144) {
    int i = (bid - 6144) * 256 + threadIdx.x;
    const int n4 = VOC * DIMC / 4;
    const int stride = 2048 * 256;
    for (; i < n4; i += stride) {
      float4 v = ((const float4*)Wout)[i];
      ushort4 u;
      u.x = f2bf(v.x); u.y = f2bf(v.y); u.z = f2bf(v.z); u.w = f2bf(v.w);
      ((ushort4*)Woutb)[i] = u;
    }
    return;
  }
  const int s = bid >> 11; bid &= 2047;
  const int tens = bid >> 10; bid &= 1023;
  const float* W; int K, N; u16 *O1, *O2; int bk, bn;
  if (tens == 0) {
    W = W1 + (size_t)s * DIMC * DFFC; K = DIMC; N = DFFC;
    O1 = W1all + (size_t)s * 2 * DFFC * DIMC;
    O2 = O1 + (size_t)DFFC * DIMC;
    bk = (bid & 15) * 64; bn = (bid >> 4) * 64;
  } else {
    W = W2 + (size_t)s * DFFC * DIMC; K = DFFC; N = DIMC;
    O1 = W2all + (size_t)s * 2 * DIMC * DFFC;
    O2 = O1 + (size_t)DIMC * DFFC;
    bk = (bid >> 4) * 64; bn = (bid & 15) * 64;
  }
  __shared__ float t[64][65];
  const int lx = threadIdx.x & 63, ly = threadIdx.x >> 6;
#pragma unroll
  for (int i = 0; i < 64; i += 4)
    t[ly + i][lx] = W[(size_t)(bk + ly + i) * N + bn + lx];
  __syncthreads();
  const int n4 = threadIdx.x >> 4;
  const int kq = (threadIdx.x & 15) * 4;
#pragma unroll
  for (int j = 0; j < 4; ++j) {
    const int n = j * 16 + n4;
    ushort4 h1, h2;
    {
      float v0 = t[kq + 0][n] * 256.f, v1 = t[kq + 1][n] * 256.f;
      float v2 = t[kq + 2][n] * 256.f, v3 = t[kq + 3][n] * 256.f;
      split16(v0, h1.x, h2.x); split16(v1, h1.y, h2.y);
      split16(v2, h1.z, h2.z); split16(v3, h1.w, h2.w);
    }
    const size_t o = (size_t)(bn + n) * K + bk + kq;
    *(ushort4*)&O1[o] = h1;
    *(ushort4*)&O2[o] = h2;
  }
}

// ============ gemm1: 256x256 tile, 8 waves (128x64), BK=32, counted-vmcnt dbuf 128KB ============
// C ~= (A1+A2)(B1+B2)^T 3-term;  act = split64(gelu(C/4096 + b1))
__global__ __launch_bounds__(512, 1) void k_mlp1(
    const u16* __restrict__ wsb,
    int offA, int pstrA,            // hn planes [TK][DIMC]
    int offB, int pstrB,            // W1t planes [DFFC][DIMC]
    const int* __restrict__ pM,
    const float* __restrict__ bias,
    u16* __restrict__ O1, u16* __restrict__ O2)
{
  const int x = blockIdx.x & 7, g = blockIdx.x >> 3;   // grid 256 = 8 x 32
  const int rb = g & 15;                               // rb-fastest
  const int cb = x * 2 + (g >> 4);                     // 2 cb per XCD (B L2-resident)
  const int M = *pM;
  if (rb * 256 >= M) return;
  const int n0 = cb * 256;

  __shared__ u16 S[2][32768];     // dbuf x [A1(16)|A2(16)|B1(16)|B2(16)] subtiles of 512u16
  const int tid = threadIdx.x, w = tid >> 6, l = tid & 63;
  const int lr16 = l & 15, hi = l >> 4;

  int goff[8];
#pragma unroll
  for (int q = 0; q < 8; ++q) {
    const int bi = w * 8 + q;
    const int side = bi >> 5;                  // 0=A, 1=B
    const int pl = (bi >> 4) & 1;
    const int j = bi & 15;
    const int row = (side ? n0 : rb * 256) + j * 16 + lr16;
    const int base = side ? (offB + pl * pstrB) : (offA + pl * pstrA);
    goff[q] = base + row * DIMC + hi * 8;
  }

  const int wr = w >> 2, wc = w & 3;           // 2M x 4N wave grid, wave tile 128x64
  f32x4 acc[8][4];
#pragma unroll
  for (int mi = 0; mi < 8; ++mi)
#pragma unroll
    for (int ni = 0; ni < 4; ++ni) acc[mi][ni] = (f32x4){0.f, 0.f, 0.f, 0.f};

  auto STAGE = [&](int buf, int kt) {
#pragma unroll
    for (int q = 0; q < 8; ++q)
      gll16(wsb + (size_t)(goff[q] + kt * 32), (void*)&S[buf][(w * 8 + q) * 512]);
  };

  STAGE(0, 0);
  STAGE(1, 1);
  const int NT = DIMC / 32;                    // 32
  for (int kt = 0; kt < NT; ++kt) {
    const int cur = kt & 1;
    if (kt + 1 < NT) asm volatile("s_waitcnt vmcnt(8)" ::: "memory");
    else             asm volatile("s_waitcnt vmcnt(0)" ::: "memory");
    __builtin_amdgcn_s_barrier();
    half8 b1v[4], b2v[4];
#pragma unroll
    for (int ni = 0; ni < 4; ++ni) {
      const int sub = (32 + wc * 4 + ni) * 512 + l * 8;
      b1v[ni] = *(const half8*)&S[cur][sub];
      b2v[ni] = *(const half8*)&S[cur][sub + 8192];
    }
#pragma unroll
    for (int mh = 0; mh < 2; ++mh) {
      half8 a1v[4], a2v[4];
#pragma unroll
      for (int i = 0; i < 4; ++i) {
        const int sub = (wr * 8 + mh * 4 + i) * 512 + l * 8;
        a1v[i] = *(const half8*)&S[cur][sub];
        a2v[i] = *(const half8*)&S[cur][sub + 8192];
      }
      __builtin_amdgcn_s_setprio(1);
#pragma unroll
      for (int i = 0; i < 4; ++i)
#pragma unroll
        for (int ni = 0; ni < 4; ++ni) {
          f32x4 c = acc[mh * 4 + i][ni];
          c = __builtin_amdgcn_mfma_f32_16x16x32_f16(a2v[i], b1v[ni], c, 0, 0, 0);
          c = __builtin_amdgcn_mfma_f32_16x16x32_f16(a1v[i], b2v[ni], c, 0, 0, 0);
          c = __builtin_amdgcn_mfma_f32_16x16x32_f16(a1v[i], b1v[ni], c, 0, 0, 0);
          acc[mh * 4 + i][ni] = c;
        }
      __builtin_amdgcn_s_setprio(0);
    }
    asm volatile("s_waitcnt lgkmcnt(0)" ::: "memory");
    __builtin_amdgcn_s_barrier();
    if (kt + 2 < NT) STAGE(cur, kt + 2);
  }

#pragma unroll
  for (int mi = 0; mi < 8; ++mi)
#pragma unroll
    for (int ni = 0; ni < 4; ++ni) {
      const int n = n0 + wc * 64 + ni * 16 + lr16;
#pragma unroll
      for (int r = 0; r < 4; ++r) {
        const int m = rb * 256 + wr * 128 + mi * 16 + hi * 4 + r;
        float v = gelu_f(acc[mi][ni][r] * (1.f / 4096.f) + bias[n]) * 64.f;
        u16 h1, h2; split16(v, h1, h2);
        O1[(size_t)m * DFFC + n] = h1;
        O2[(size_t)m * DFFC + n] = h2;
      }
    }
}

// ============ gemm2: 256x128 tile, split-K2, 8 waves (64x64), BK=32, dbuf 96KB ============
// counted-vmcnt (R12-proven).  PO[z-slab] = C/16384
__global__ __launch_bounds__(512, 1) void k_mlp2(
    const u16* __restrict__ wsb,
    int offA, int pstrA,            // act planes [TK][DFFC]
    int offB, int pstrB,            // W2t planes [DIMC][DFFC]
    const int* __restrict__ pM,
    float* __restrict__ PO)
{
  const int x = blockIdx.x & 7, g = blockIdx.x >> 3;   // grid 256 = 8 x 32
  const int rb = g & 15;
  const int cz = x * 2 + (g >> 4);                     // 0..15
  const int cb = cz & 7, z = cz >> 3;
  const int M = *pM;
  if (rb * 256 >= M) return;
  const int n0 = cb * 128;
  const int kz = z * 2048;

  __shared__ u16 S[2][24576];     // dbuf x [A1(16)|A2(16)|B1(8)|B2(8)] subtiles of 512u16
  const int tid = threadIdx.x, w = tid >> 6, l = tid & 63;
  const int lr16 = l & 15, hi = l >> 4;

  int goff[6];
#pragma unroll
  for (int q = 0; q < 6; ++q) {
    const int bi = w * 6 + q;
    int base, row;
    if (bi < 32) {
      const int pl = bi >> 4, j = bi & 15;
      base = offA + pl * pstrA;
      row = rb * 256 + j * 16 + lr16;
    } else {
      const int bb = bi - 32, pl = bb >> 3, j = bb & 7;
      base = offB + pl * pstrB;
      row = n0 + j * 16 + lr16;
    }
    goff[q] = base + row * DFFC + kz + hi * 8;
  }

  const int wr = w >> 1, wc = w & 1;           // 4M x 2N wave grid, wave tile 64x64
  f32x4 acc[4][4];
#pragma unroll
  for (int mi = 0; mi < 4; ++mi)
#pragma unroll
    for (int ni = 0; ni < 4; ++ni) acc[mi][ni] = (f32x4){0.f, 0.f, 0.f, 0.f};

  auto STAGE = [&](int buf, int kt) {
#pragma unroll
    for (int q = 0; q < 6; ++q)
      gll16(wsb + (size_t)(goff[q] + kt * 32), (void*)&S[buf][(w * 6 + q) * 512]);
  };

  STAGE(0, 0);
  STAGE(1, 1);
  const int NT = 2048 / 32;                    // 64
  for (int kt = 0; kt < NT; ++kt) {
    const int cur = kt & 1;
    if (kt + 1 < NT) asm volatile("s_waitcnt vmcnt(6)" ::: "memory");
    else             asm volatile("s_waitcnt vmcnt(0)" ::: "memory");
    __builtin_amdgcn_s_barrier();
    half8 a1v[4], a2v[4], b1v[4], b2v[4];
#pragma unroll
    for (int mi = 0; mi < 4; ++mi) {
      const int sub = (wr * 4 + mi) * 512 + l * 8;
      a1v[mi] = *(const half8*)&S[cur][sub];
      a2v[mi] = *(const half8*)&S[cur][sub + 8192];
    }
#pragma unroll
    for (int ni = 0; ni < 4; ++ni) {
      const int sub = (32 + wc * 4 + ni) * 512 + l * 8;
      b1v[ni] = *(const half8*)&S[cur][sub];
      b2v[ni] = *(const half8*)&S[cur][sub + 4096];
    }
    __builtin_amdgcn_s_setprio(1);
#pragma unroll
    for (int mi = 0; mi < 4; ++mi)
#pragma unroll
      for (int ni = 0; ni < 4; ++ni) {
        f32x4 c = acc[mi][ni];
        c = __builtin_amdgcn_mfma_f32_16x16x32_f16(a2v[mi], b1v[ni], c, 0, 0, 0);
        c = __builtin_amdgcn_mfma_f32_16x16x32_f16(a1v[mi], b2v[ni], c, 0, 0, 0);
        c = __builtin_amdgcn_mfma_f32_16x16x32_f16(a1v[mi], b1v[ni], c, 0, 0, 0);
        acc[mi][ni] = c;
      }
    __builtin_amdgcn_s_setprio(0);
    asm volatile("s_waitcnt lgkmcnt(0)" ::: "memory");
    __builtin_amdgcn_s_barrier();
    if (kt + 2 < NT) STAGE(cur, kt + 2);
  }

#pragma unroll
  for (int mi = 0; mi < 4; ++mi)
#pragma unroll
    for (int ni = 0; ni < 4; ++ni) {
      const int n = n0 + wc * 64 + ni * 16 + lr16;
#pragma unroll
      for (int r = 0; r < 4; ++r) {
        const int m = rb * 256 + wr * 64 + mi * 16 + hi * 4 + r;
        PO[(size_t)(z * TK + m) * DIMC + n] = acc[mi][ni][r] * (1.f / 16384.f);
      }
    }
}

// ---------------- decide: o = h + p0 + p1 + b2; cos; route; fused next-stage LN ----------------
__global__ __launch_bounds__(256) void k_decide(
    float* __restrict__ h, const float* __restrict__ p,
    const float* __restrict__ bias,
    const int* __restrict__ surv_in, int* __restrict__ surv_out,
    const int* __restrict__ pM, int* __restrict__ cnts,
    int* __restrict__ exit_idx, u16* __restrict__ hexit,
    const float* __restrict__ gnx, const float* __restrict__ bnx,
    u16* __restrict__ hn1, u16* __restrict__ hn2,
    int stage)
{
  const int bidx = blockIdx.x;
  if (bidx >= *pM) return;
  const int t = surv_in[bidx];
  const int tid = threadIdx.x;
  const int lane = tid & 63, wid = tid >> 6;
  __shared__ float sm[16];
  __shared__ int sif[2];
  float4 a  = ((const float4*)(h + (size_t)t * DIMC))[tid];
  float4 p0 = ((const float4*)(p + (size_t)bidx * DIMC))[tid];
  float4 p1 = ((const float4*)(p + (size_t)(TK + bidx) * DIMC))[tid];
  float4 bb = ((const float4*)bias)[tid];
  float4 o;
  o.x = a.x + p0.x + p1.x + bb.x;
  o.y = a.y + p0.y + p1.y + bb.y;
  o.z = a.z + p0.z + p1.z + bb.z;
  o.w = a.w + p0.w + p1.w + bb.w;
  float hh = a.x * a.x + a.y * a.y + a.z * a.z + a.w * a.w;
  float ho = a.x * o.x + a.y * o.y + a.z * o.z + a.w * o.w;
  float oo = o.x * o.x + o.y * o.y + o.z * o.z + o.w * o.w;
  float so = o.x + o.y + o.z + o.w;
#pragma unroll
  for (int off = 32; off; off >>= 1) {
    hh += __shfl_down(hh, off);
    ho += __shfl_down(ho, off);
    oo += __shfl_down(oo, off);
    so += __shfl_down(so, off);
  }
  if (lane == 0) { sm[wid] = hh; sm[4 + wid] = ho; sm[8 + wid] = oo; sm[12 + wid] = so; }
  __syncthreads();
  // mean of o (read before sm reuse); same summation order as the old k_ln
  const float mean = (sm[12] + sm[13] + sm[14] + sm[15]) * (1.0f / DIMC);
  if (tid == 0) {
    int take;
    if (stage == NL - 1) take = 1;
    else {
      const float HH = sm[0] + sm[1] + sm[2] + sm[3];
      const float HO = sm[4] + sm[5] + sm[6] + sm[7];
      const float OO = sm[8] + sm[9] + sm[10] + sm[11];
      const float cosv = HO / (sqrtf(HH) * sqrtf(OO) + 1e-8f);
      take = (cosv >= 0.98f) ? 1 : 0;
    }
    int pos;
    if (take) {
      pos = atomicAdd(&cnts[stage], 1);
      exit_idx[pos] = t;
    } else {
      pos = atomicAdd(&cnts[4 + stage], 1);
      surv_out[pos] = t;
    }
    sif[0] = take; sif[1] = pos;
  }
  __syncthreads();
  if (sif[0]) {
    u16* dst = hexit + (size_t)sif[1] * DIMC;
    ushort4 u;
    u.x = f2bf(o.x); u.y = f2bf(o.y); u.z = f2bf(o.z); u.w = f2bf(o.w);
    ((ushort4*)dst)[tid] = u;
  } else {
    // survivor: write back h, and fused LN for next stage into hn[pos]
    ((float4*)(h + (size_t)t * DIMC))[tid] = o;
    float4 d;
    d.x = o.x - mean; d.y = o.y - mean; d.z = o.z - mean; d.w = o.w - mean;
    float q = d.x * d.x + d.y * d.y + d.z * d.z + d.w * d.w;
#pragma unroll
    for (int off = 32; off; off >>= 1) q += __shfl_down(q, off);
    if (lane == 0) sm[wid] = q;
    __syncthreads();
    const float var = (sm[0] + sm[1] + sm[2] + sm[3]) * (1.0f / DIMC);
    const float rstd = 1.0f / sqrtf(var + 1e-5f);
    float4 gg = ((const float4*)gnx)[tid];
    float4 b2 = ((const float4*)bnx)[tid];
    float o4[4];
    o4[0] = (d.x * rstd * gg.x + b2.x) * 16.f;
    o4[1] = (d.y * rstd * gg.y + b2.y) * 16.f;
    o4[2] = (d.z * rstd * gg.z + b2.z) * 16.f;
    o4[3] = (d.w * rstd * gg.w + b2.w) * 16.f;
    ushort4 u1, u2;
    split16(o4[0], u1.x, u2.x); split16(o4[1], u1.y, u2.y);
    split16(o4[2], u1.z, u2.z); split16(o4[3], u1.w, u2.w);
    const int pos = sif[1];
    ((ushort4*)(hn1 + (size_t)pos * DIMC))[tid] = u1;
    ((ushort4*)(hn2 + (size_t)pos * DIMC))[tid] = u2;
  }
}

// ============ logits: bf16, 256x128 tile, BK=32, dbuf 48KB, 8 waves, 2 blk/CU ============
// counted-vmcnt, rb-fastest XCD-partitioned swizzle (R12-proven; unchanged).
__global__ __launch_bounds__(512, 4) void k_logits(
    const u16* __restrict__ wsb, int offA, int offB,
    const int* __restrict__ pcnt,
    const int* __restrict__ exit_idx,
    float* __restrict__ out)
{
  const int x = blockIdx.x & 7, g = blockIdx.x >> 3;   // grid 4096 = 8 x 512
  const int rb = g & 15;
  const int cb = x * 32 + (g >> 4);                    // 0..255
  if (cb >= VOC / 128) return;                         // 250 real cb
  const int cnt = *pcnt;
  if (rb * 256 >= cnt) return;
  const int n0 = cb * 128;

  __shared__ u16 S[2][12288];          // [A(16 subtiles) | B(8 subtiles)] x 512u16; 48KB
  const int tid = threadIdx.x, w = tid >> 6, l = tid & 63;
  const int lr16 = l & 15, hi = l >> 4;

  int goff[3], loff[3];
#pragma unroll
  for (int q = 0; q < 3; ++q) {
    const int bi = w * 3 + q;          // 24 subtiles: A 0..15, B 16..23
    if (bi < 16) {
      goff[q] = offA + (rb * 256 + bi * 16 + lr16) * DIMC + hi * 8;
      loff[q] = bi * 512;
    } else {
      const int j = bi - 16;
      goff[q] = offB + (n0 + j * 16 + lr16) * DIMC + hi * 8;
      loff[q] = 8192 + j * 512;
    }
  }

  const int wr = w >> 1, wc = w & 1;   // 4M x 2N wave grid, wave tile 64x64
  f32x4 acc[4][4];
#pragma unroll
  for (int mi = 0; mi < 4; ++mi)
#pragma unroll
    for (int ni = 0; ni < 4; ++ni) acc[mi][ni] = (f32x4){0.f, 0.f, 0.f, 0.f};

  auto STAGE = [&](int buf, int kt) {
#pragma unroll
    for (int q = 0; q < 3; ++q)
      gll16(wsb + (size_t)(goff[q] + kt * 32), (void*)&S[buf][loff[q]]);
  };

  STAGE(0, 0);
  STAGE(1, 1);
  const int NT = DIMC / 32;            // 32
  for (int kt = 0; kt < NT; ++kt) {
    const int cur = kt & 1;
    if (kt + 1 < NT) asm volatile("s_waitcnt vmcnt(3)" ::: "memory");
    else             asm volatile("s_waitcnt vmcnt(0)" ::: "memory");
    __builtin_amdgcn_s_barrier();
    bf16x8 aF[4], bF[4];
#pragma unroll
    for (int mi = 0; mi < 4; ++mi)
      aF[mi] = *(const bf16x8*)&S[cur][(wr * 4 + mi) * 512 + l * 8];
#pragma unroll
    for (int ni = 0; ni < 4; ++ni)
      bF[ni] = *(const bf16x8*)&S[cur][8192 + (wc * 4 + ni) * 512 + l * 8];
    __builtin_amdgcn_s_setprio(1);
#pragma unroll
    for (int mi = 0; mi < 4; ++mi)
#pragma unroll
      for (int ni = 0; ni < 4; ++ni)
        acc[mi][ni] = __builtin_amdgcn_mfma_f32_16x16x32_bf16(aF[mi], bF[ni], acc[mi][ni], 0, 0, 0);
    __builtin_amdgcn_s_setprio(0);
    asm volatile("s_waitcnt lgkmcnt(0)" ::: "memory");
    __builtin_amdgcn_s_barrier();
    if (kt + 2 < NT) STAGE(cur, kt + 2);
  }

  const int mvalid = cnt - rb * 256;
#pragma unroll
  for (int mi = 0; mi < 4; ++mi)
#pragma unroll
    for (int r = 0; r < 4; ++r) {
      const int mrow = wr * 64 + mi * 16 + hi * 4 + r;
      if (mrow < mvalid) {
        const int tok = exit_idx[rb * 256 + mrow];
        float* orow = out + (size_t)tok * VOC + n0 + wc * 64 + lr16;
#pragma unroll
        for (int ni = 0; ni < 4; ++ni)
          __builtin_nontemporal_store(acc[mi][ni][r], &orow[ni * 16]);
      }
    }
}

// ---------------- host ----------------
extern "C" void kernel_launch(void* const* d_in, const int* in_sizes, int n_in,
                              void* d_out, int out_size, void* d_ws, size_t ws_size,
                              hipStream_t stream)
{
  const int*   x    = (const int*)d_in[0];
  const float* emb  = (const float*)d_in[1];
  const float* ln_g = (const float*)d_in[2];
  const float* ln_b = (const float*)d_in[3];
  const float* W1   = (const float*)d_in[4];
  const float* b1   = (const float*)d_in[5];
  const float* W2   = (const float*)d_in[6];
  const float* b2   = (const float*)d_in[7];
  const float* Wout = (const float*)d_in[8];
  float* out = (float*)d_out;

  char* p = (char*)d_ws;
  size_t off = 0;
  auto alloc = [&](size_t bytes) -> void* {
    void* r = p + off;
    off += (bytes + 255) & ~(size_t)255;
    return r;
  };
  u16* wsb = (u16*)d_ws;
  float* h    = (float*)alloc((size_t)TK * DIMC * 4);
  float* pbuf = (float*)alloc((size_t)2 * TK * DIMC * 4);   // gemm2 split-K partials
  u16* hn1 = (u16*)alloc((size_t)2 * TK * DIMC * 2);        // dedicated (decide writes it)
  u16* hn2 = hn1 + (size_t)TK * DIMC;
  u16* act1 = (u16*)alloc((size_t)2 * TK * DFFC * 2);       // act1 | act2 contiguous
  u16* act2 = act1 + (size_t)TK * DFFC;
  u16* Woutb = (u16*)alloc((size_t)VOC * DIMC * 2);
  u16* W1all = (u16*)alloc((size_t)NL * 2 * DFFC * DIMC * 2);  // 3 stages x 2 planes
  u16* W2all = (u16*)alloc((size_t)NL * 2 * DIMC * DFFC * 2);
  u16* hexit = (u16*)alloc((size_t)TK * DIMC * 2);
  int* exit_idx = (int*)alloc((size_t)TK * 4);
  int* surv_a   = (int*)alloc((size_t)TK * 4);
  int* surv_b   = (int*)alloc((size_t)TK * 4);
  int* cnts     = (int*)alloc(64 * 4);
  // cnts[0..2]=exit counts; cnts[4..6]=survivor counts; cnts[12]=TK

  const int offHn  = (int)(hn1  - wsb);
  const int offAct = (int)(act1 - wsb);
  const int offWob = (int)(Woutb- wsb);
  const int offW1a = (int)(W1all- wsb);
  const int offW2a = (int)(W2all- wsb);
  const int offHex = (int)(hexit- wsb);
  const int pstrHn  = TK * DIMC;
  const int pstrAct = TK * DFFC;
  const int pstrW   = DFFC * DIMC;

  k_init<<<TK, 256, 0, stream>>>(x, emb, ln_g, ln_b, h, hn1, hn2, surv_a, cnts);
  k_prep<<<8192, 256, 0, stream>>>(W1, W2, W1all, W2all, Wout, Woutb);
  int* surv_in  = surv_a;
  int* surv_out = surv_b;
  for (int i = 0; i < NL; ++i) {
    const int* pM = (i == 0) ? (cnts + 12) : (cnts + 4 + (i - 1));
    // gemm1: grid 256 = 8 XCD x (16 rb x 2 cbl)
    k_mlp1<<<256, 512, 0, stream>>>(
        wsb, offHn, pstrHn, offW1a + i * 2 * pstrW, pstrW,
        pM, b1 + (size_t)i * DFFC, act1, act2);
    // gemm2: grid 256 = 8 XCD x (16 rb x 2 cz), split-K2
    k_mlp2<<<256, 512, 0, stream>>>(
        wsb, offAct, pstrAct, offW2a + i * 2 * pstrW, pstrW, pM, pbuf);
    // decide + fused LN for stage i+1 (gnx/bnx unused at last stage)
    const int inx = (i + 1 < NL) ? (i + 1) : i;
    k_decide<<<TK, 256, 0, stream>>>(h, pbuf, b2 + (size_t)i * DIMC,
        surv_in, surv_out, pM, cnts, exit_idx, hexit,
        ln_g + (size_t)inx * DIMC, ln_b + (size_t)inx * DIMC, hn1, hn2, i);
    // logits: grid 4096 = 8 XCD x (16 rb x 32 cbl), cb>=250 idle
    k_logits<<<4096, 512, 0, stream>>>(wsb, offHex, offWob, cnts + i, exit_idx, out);
    int* tmp = surv_in; surv_in = surv_out; surv_out = tmp;
  }
}

// Round 15
// 1323.434 us; speedup vs baseline: 1.0568x; 1.0339x over previous
//
#include <hip/hip_runtime.h>
#include <hip/hip_bf16.h>
#include <stdint.h>

constexpr int TK   = 4096;   // B*S tokens
constexpr int DIMC = 1024;
constexpr int DFFC = 4096;
constexpr int VOC  = 32000;
constexpr int NL   = 3;

typedef __attribute__((ext_vector_type(8))) short bf16x8;
typedef __attribute__((ext_vector_type(8))) _Float16 half8;
typedef __attribute__((ext_vector_type(4))) float f32x4;
using u16 = unsigned short;

__device__ __forceinline__ u16 f2bf(float f) {
  unsigned int u = __float_as_uint(f);
  u += 0x7FFF + ((u >> 16) & 1);           // RNE; inputs finite
  return (u16)(u >> 16);
}

__device__ __forceinline__ void split16(float v, u16& hi, u16& lo) {
  _Float16 a = (_Float16)v;
  _Float16 b = (_Float16)(v - (float)a);
  hi = __builtin_bit_cast(u16, a);
  lo = __builtin_bit_cast(u16, b);
}

__device__ __forceinline__ float gelu_f(float x) {
  float x3 = x * x * x;
  return 0.5f * x * (1.0f + tanhf(0.7978845608028654f * (x + 0.044715f * x3)));
}

// async global->LDS, 16B/lane; LDS dest = wave-uniform base (+lane*16 in HW)
__device__ __forceinline__ void gll16(const void* g, void* l) {
  __builtin_amdgcn_global_load_lds(
      (const __attribute__((address_space(1))) unsigned int*)g,
      (__attribute__((address_space(3))) unsigned int*)l, 16, 0, 0);
}

// ---------------- init: gather emb + stage-0 LN -> hn planes ----------------
__global__ __launch_bounds__(256) void k_init(const int* __restrict__ x,
    const float* __restrict__ emb,
    const float* __restrict__ g, const float* __restrict__ b,
    float* __restrict__ h, u16* __restrict__ hn1, u16* __restrict__ hn2,
    int* __restrict__ surv, int* __restrict__ cnts) {
  const int t = blockIdx.x, tid = threadIdx.x;
  if (t == 0 && tid < 16) cnts[tid] = (tid == 12) ? TK : 0;
  if (tid == 0) surv[t] = t;
  const int tok = x[t];
  const int lane = tid & 63, wid = tid >> 6;
  __shared__ float sm[4];
  float4 v = ((const float4*)(emb + (size_t)tok * DIMC))[tid];
  ((float4*)(h + (size_t)t * DIMC))[tid] = v;
  float s = v.x + v.y + v.z + v.w;
#pragma unroll
  for (int o = 32; o; o >>= 1) s += __shfl_down(s, o);
  if (lane == 0) sm[wid] = s;
  __syncthreads();
  const float mean = (sm[0] + sm[1] + sm[2] + sm[3]) * (1.0f / DIMC);
  __syncthreads();
  float4 d;
  d.x = v.x - mean; d.y = v.y - mean; d.z = v.z - mean; d.w = v.w - mean;
  float q = d.x * d.x + d.y * d.y + d.z * d.z + d.w * d.w;
#pragma unroll
  for (int o = 32; o; o >>= 1) q += __shfl_down(q, o);
  if (lane == 0) sm[wid] = q;
  __syncthreads();
  const float var = (sm[0] + sm[1] + sm[2] + sm[3]) * (1.0f / DIMC);
  const float rstd = 1.0f / sqrtf(var + 1e-5f);
  float4 gg = ((const float4*)g)[tid];
  float4 bb = ((const float4*)b)[tid];
  float o4[4];
  o4[0] = (d.x * rstd * gg.x + bb.x) * 16.f;
  o4[1] = (d.y * rstd * gg.y + bb.y) * 16.f;
  o4[2] = (d.z * rstd * gg.z + bb.z) * 16.f;
  o4[3] = (d.w * rstd * gg.w + bb.w) * 16.f;
  ushort4 u1, u2;
  split16(o4[0], u1.x, u2.x); split16(o4[1], u1.y, u2.y);
  split16(o4[2], u1.z, u2.z); split16(o4[3], u1.w, u2.w);
  ((ushort4*)(hn1 + (size_t)t * DIMC))[tid] = u1;
  ((ushort4*)(hn2 + (size_t)t * DIMC))[tid] = u2;
}

// ---------------- prep: ALL weight transposes/splits + Wout->bf16, one dispatch ----------------
__global__ __launch_bounds__(256) void k_prep(
    const float* __restrict__ W1, const float* __restrict__ W2,
    u16* __restrict__ W1all, u16* __restrict__ W2all,
    const float* __restrict__ Wout, u16* __restrict__ Woutb)
{
  int bid = blockIdx.x;
  if (bid >= 6144) {
    int i = (bid - 6144) * 256 + threadIdx.x;
    const int n4 = VOC * DIMC / 4;
    const int stride = 2048 * 256;
    for (; i < n4; i += stride) {
      float4 v = ((const float4*)Wout)[i];
      ushort4 u;
      u.x = f2bf(v.x); u.y = f2bf(v.y); u.z = f2bf(v.z); u.w = f2bf(v.w);
      ((ushort4*)Woutb)[i] = u;
    }
    return;
  }
  const int s = bid >> 11; bid &= 2047;
  const int tens = bid >> 10; bid &= 1023;
  const float* W; int K, N; u16 *O1, *O2; int bk, bn;
  if (tens == 0) {
    W = W1 + (size_t)s * DIMC * DFFC; K = DIMC; N = DFFC;
    O1 = W1all + (size_t)s * 2 * DFFC * DIMC;
    O2 = O1 + (size_t)DFFC * DIMC;
    bk = (bid & 15) * 64; bn = (bid >> 4) * 64;
  } else {
    W = W2 + (size_t)s * DFFC * DIMC; K = DFFC; N = DIMC;
    O1 = W2all + (size_t)s * 2 * DIMC * DFFC;
    O2 = O1 + (size_t)DIMC * DFFC;
    bk = (bid >> 4) * 64; bn = (bid & 15) * 64;
  }
  __shared__ float t[64][65];
  const int lx = threadIdx.x & 63, ly = threadIdx.x >> 6;
#pragma unroll
  for (int i = 0; i < 64; i += 4)
    t[ly + i][lx] = W[(size_t)(bk + ly + i) * N + bn + lx];
  __syncthreads();
  const int n4 = threadIdx.x >> 4;
  const int kq = (threadIdx.x & 15) * 4;
#pragma unroll
  for (int j = 0; j < 4; ++j) {
    const int n = j * 16 + n4;
    ushort4 h1, h2;
    {
      float v0 = t[kq + 0][n] * 256.f, v1 = t[kq + 1][n] * 256.f;
      float v2 = t[kq + 2][n] * 256.f, v3 = t[kq + 3][n] * 256.f;
      split16(v0, h1.x, h2.x); split16(v1, h1.y, h2.y);
      split16(v2, h1.z, h2.z); split16(v3, h1.w, h2.w);
    }
    const size_t o = (size_t)(bn + n) * K + bk + kq;
    *(ushort4*)&O1[o] = h1;
    *(ushort4*)&O2[o] = h2;
  }
}

// ============ gemm1: 256x256 tile, 8 waves (128x64), BK=32, dbuf 128KB ============
// m201-style 4-phase interleave: each phase {ds_read pair, stage-issue, barrier,
// lgkmcnt(0), setprio+24 MFMA, barrier}; vmcnt(0) once per kt (full-kt flight).
// C ~= (A1+A2)(B1+B2)^T 3-term;  act = split64(gelu(C/4096 + b1))
__global__ __launch_bounds__(512, 1) void k_mlp1(
    const u16* __restrict__ wsb,
    int offA, int pstrA,            // hn planes [TK][DIMC]
    int offB, int pstrB,            // W1t planes [DFFC][DIMC]
    const int* __restrict__ pM,
    const float* __restrict__ bias,
    u16* __restrict__ O1, u16* __restrict__ O2)
{
  const int x = blockIdx.x & 7, g = blockIdx.x >> 3;   // grid 256 = 8 x 32
  const int rb = g & 15;                               // rb-fastest
  const int cb = x * 2 + (g >> 4);                     // 2 cb per XCD (B L2-resident)
  const int M = *pM;
  if (rb * 256 >= M) return;
  const int n0 = cb * 256;

  __shared__ u16 S[2][32768];     // dbuf x [A1(16)|A2(16)|B1(16)|B2(16)] subtiles of 512u16
  const int tid = threadIdx.x, w = tid >> 6, l = tid & 63;
  const int lr16 = l & 15, hi = l >> 4;

  int goff[8];
#pragma unroll
  for (int q = 0; q < 8; ++q) {
    const int bi = w * 8 + q;
    const int side = bi >> 5;                  // 0=A, 1=B
    const int pl = (bi >> 4) & 1;
    const int j = bi & 15;
    const int row = (side ? n0 : rb * 256) + j * 16 + lr16;
    const int base = side ? (offB + pl * pstrB) : (offA + pl * pstrA);
    goff[q] = base + row * DIMC + hi * 8;
  }

  const int wr = w >> 2, wc = w & 3;           // 2M x 4N wave grid, wave tile 128x64
  f32x4 acc[8][4];
#pragma unroll
  for (int mi = 0; mi < 8; ++mi)
#pragma unroll
    for (int ni = 0; ni < 4; ++ni) acc[mi][ni] = (f32x4){0.f, 0.f, 0.f, 0.f};

  auto STAGE_H = [&](int buf, int kt, int h4) {   // 4 loads: q = h4*4..h4*4+3
#pragma unroll
    for (int q = h4 * 4; q < h4 * 4 + 4; ++q)
      gll16(wsb + (size_t)(goff[q] + kt * 32), (void*)&S[buf][(w * 8 + q) * 512]);
  };

  STAGE_H(0, 0, 0); STAGE_H(0, 0, 1);
  const int NT = DIMC / 32;                    // 32
  for (int kt = 0; kt < NT; ++kt) {
    const int cur = kt & 1;
    asm volatile("s_waitcnt vmcnt(0)" ::: "memory");   // buf[cur] loads done
    __builtin_amdgcn_s_barrier();
    half8 b1v[4], b2v[4];
#pragma unroll
    for (int ph = 0; ph < 4; ++ph) {
      half8 a1v[2], a2v[2];
      if (ph == 0) {
#pragma unroll
        for (int ni = 0; ni < 4; ++ni) {
          const int sub = (32 + wc * 4 + ni) * 512 + l * 8;
          b1v[ni] = *(const half8*)&S[cur][sub];
          b2v[ni] = *(const half8*)&S[cur][sub + 8192];
        }
      }
#pragma unroll
      for (int i = 0; i < 2; ++i) {
        const int sub = (wr * 8 + ph * 2 + i) * 512 + l * 8;
        a1v[i] = *(const half8*)&S[cur][sub];
        a2v[i] = *(const half8*)&S[cur][sub + 8192];
      }
      if (ph < 2 && kt + 1 < NT) STAGE_H(cur ^ 1, kt + 1, ph);  // front-loaded prefetch
      asm volatile("s_waitcnt lgkmcnt(0)" ::: "memory");
      __builtin_amdgcn_s_setprio(1);
#pragma unroll
      for (int i = 0; i < 2; ++i)
#pragma unroll
        for (int ni = 0; ni < 4; ++ni) {
          f32x4 c = acc[ph * 2 + i][ni];
          c = __builtin_amdgcn_mfma_f32_16x16x32_f16(a2v[i], b1v[ni], c, 0, 0, 0);
          c = __builtin_amdgcn_mfma_f32_16x16x32_f16(a1v[i], b2v[ni], c, 0, 0, 0);
          c = __builtin_amdgcn_mfma_f32_16x16x32_f16(a1v[i], b1v[ni], c, 0, 0, 0);
          acc[ph * 2 + i][ni] = c;
        }
      __builtin_amdgcn_s_setprio(0);
      __builtin_amdgcn_s_barrier();
    }
  }

#pragma unroll
  for (int mi = 0; mi < 8; ++mi)
#pragma unroll
    for (int ni = 0; ni < 4; ++ni) {
      const int n = n0 + wc * 64 + ni * 16 + lr16;
#pragma unroll
      for (int r = 0; r < 4; ++r) {
        const int m = rb * 256 + wr * 128 + mi * 16 + hi * 4 + r;
        float v = gelu_f(acc[mi][ni][r] * (1.f / 4096.f) + bias[n]) * 64.f;
        u16 h1, h2; split16(v, h1, h2);
        O1[(size_t)m * DFFC + n] = h1;
        O2[(size_t)m * DFFC + n] = h2;
      }
    }
}

// ============ gemm2: 256x128 tile, split-K2, 8 waves (64x64), BK=32, dbuf 96KB ============
// m201-style 2-phase interleave; vmcnt(0) once per kt.  PO[z-slab] = C/16384
__global__ __launch_bounds__(512, 1) void k_mlp2(
    const u16* __restrict__ wsb,
    int offA, int pstrA,            // act planes [TK][DFFC]
    int offB, int pstrB,            // W2t planes [DIMC][DFFC]
    const int* __restrict__ pM,
    float* __restrict__ PO)
{
  const int x = blockIdx.x & 7, g = blockIdx.x >> 3;   // grid 256 = 8 x 32
  const int rb = g & 15;
  const int cz = x * 2 + (g >> 4);                     // 0..15
  const int cb = cz & 7, z = cz >> 3;
  const int M = *pM;
  if (rb * 256 >= M) return;
  const int n0 = cb * 128;
  const int kz = z * 2048;

  __shared__ u16 S[2][24576];     // dbuf x [A1(16)|A2(16)|B1(8)|B2(8)] subtiles of 512u16
  const int tid = threadIdx.x, w = tid >> 6, l = tid & 63;
  const int lr16 = l & 15, hi = l >> 4;

  int goff[6];
#pragma unroll
  for (int q = 0; q < 6; ++q) {
    const int bi = w * 6 + q;
    int base, row;
    if (bi < 32) {
      const int pl = bi >> 4, j = bi & 15;
      base = offA + pl * pstrA;
      row = rb * 256 + j * 16 + lr16;
    } else {
      const int bb = bi - 32, pl = bb >> 3, j = bb & 7;
      base = offB + pl * pstrB;
      row = n0 + j * 16 + lr16;
    }
    goff[q] = base + row * DFFC + kz + hi * 8;
  }

  const int wr = w >> 1, wc = w & 1;           // 4M x 2N wave grid, wave tile 64x64
  f32x4 acc[4][4];
#pragma unroll
  for (int mi = 0; mi < 4; ++mi)
#pragma unroll
    for (int ni = 0; ni < 4; ++ni) acc[mi][ni] = (f32x4){0.f, 0.f, 0.f, 0.f};

  auto STAGE_H = [&](int buf, int kt, int h3) {   // 3 loads: q = h3*3..h3*3+2
#pragma unroll
    for (int q = h3 * 3; q < h3 * 3 + 3; ++q)
      gll16(wsb + (size_t)(goff[q] + kt * 32), (void*)&S[buf][(w * 6 + q) * 512]);
  };

  STAGE_H(0, 0, 0); STAGE_H(0, 0, 1);
  const int NT = 2048 / 32;                    // 64
  for (int kt = 0; kt < NT; ++kt) {
    const int cur = kt & 1;
    asm volatile("s_waitcnt vmcnt(0)" ::: "memory");
    __builtin_amdgcn_s_barrier();
    half8 a1v[4], a2v[4];
#pragma unroll
    for (int ph = 0; ph < 2; ++ph) {
      half8 b1v[2], b2v[2];
      if (ph == 0) {
#pragma unroll
        for (int mi = 0; mi < 4; ++mi) {
          const int sub = (wr * 4 + mi) * 512 + l * 8;
          a1v[mi] = *(const half8*)&S[cur][sub];
          a2v[mi] = *(const half8*)&S[cur][sub + 8192];
        }
      }
#pragma unroll
      for (int ni = 0; ni < 2; ++ni) {
        const int sub = (32 + wc * 4 + ph * 2 + ni) * 512 + l * 8;
        b1v[ni] = *(const half8*)&S[cur][sub];
        b2v[ni] = *(const half8*)&S[cur][sub + 4096];
      }
      if (kt + 1 < NT) STAGE_H(cur ^ 1, kt + 1, ph);
      asm volatile("s_waitcnt lgkmcnt(0)" ::: "memory");
      __builtin_amdgcn_s_setprio(1);
#pragma unroll
      for (int mi = 0; mi < 4; ++mi)
#pragma unroll
        for (int ni = 0; ni < 2; ++ni) {
          f32x4 c = acc[mi][ph * 2 + ni];
          c = __builtin_amdgcn_mfma_f32_16x16x32_f16(a2v[mi], b1v[ni], c, 0, 0, 0);
          c = __builtin_amdgcn_mfma_f32_16x16x32_f16(a1v[mi], b2v[ni], c, 0, 0, 0);
          c = __builtin_amdgcn_mfma_f32_16x16x32_f16(a1v[mi], b1v[ni], c, 0, 0, 0);
          acc[mi][ph * 2 + ni] = c;
        }
      __builtin_amdgcn_s_setprio(0);
      __builtin_amdgcn_s_barrier();
    }
  }

#pragma unroll
  for (int mi = 0; mi < 4; ++mi)
#pragma unroll
    for (int ni = 0; ni < 4; ++ni) {
      const int n = n0 + wc * 64 + ni * 16 + lr16;
#pragma unroll
      for (int r = 0; r < 4; ++r) {
        const int m = rb * 256 + wr * 64 + mi * 16 + hi * 4 + r;
        PO[(size_t)(z * TK + m) * DIMC + n] = acc[mi][ni][r] * (1.f / 16384.f);
      }
    }
}

// ---------------- decide: o = h + p0 + p1 + b2; cos; route; fused next-stage LN ----------------
__global__ __launch_bounds__(256) void k_decide(
    float* __restrict__ h, const float* __restrict__ p,
    const float* __restrict__ bias,
    const int* __restrict__ surv_in, int* __restrict__ surv_out,
    const int* __restrict__ pM, int* __restrict__ cnts,
    int* __restrict__ exit_idx, u16* __restrict__ hexit,
    const float* __restrict__ gnx, const float* __restrict__ bnx,
    u16* __restrict__ hn1, u16* __restrict__ hn2,
    int stage)
{
  const int bidx = blockIdx.x;
  if (bidx >= *pM) return;
  const int t = surv_in[bidx];
  const int tid = threadIdx.x;
  const int lane = tid & 63, wid = tid >> 6;
  __shared__ float sm[16];
  __shared__ int sif[2];
  float4 a  = ((const float4*)(h + (size_t)t * DIMC))[tid];
  float4 p0 = ((const float4*)(p + (size_t)bidx * DIMC))[tid];
  float4 p1 = ((const float4*)(p + (size_t)(TK + bidx) * DIMC))[tid];
  float4 bb = ((const float4*)bias)[tid];
  float4 o;
  o.x = a.x + p0.x + p1.x + bb.x;
  o.y = a.y + p0.y + p1.y + bb.y;
  o.z = a.z + p0.z + p1.z + bb.z;
  o.w = a.w + p0.w + p1.w + bb.w;
  float hh = a.x * a.x + a.y * a.y + a.z * a.z + a.w * a.w;
  float ho = a.x * o.x + a.y * o.y + a.z * o.z + a.w * o.w;
  float oo = o.x * o.x + o.y * o.y + o.z * o.z + o.w * o.w;
  float so = o.x + o.y + o.z + o.w;
#pragma unroll
  for (int off = 32; off; off >>= 1) {
    hh += __shfl_down(hh, off);
    ho += __shfl_down(ho, off);
    oo += __shfl_down(oo, off);
    so += __shfl_down(so, off);
  }
  if (lane == 0) { sm[wid] = hh; sm[4 + wid] = ho; sm[8 + wid] = oo; sm[12 + wid] = so; }
  __syncthreads();
  const float mean = (sm[12] + sm[13] + sm[14] + sm[15]) * (1.0f / DIMC);
  if (tid == 0) {
    int take;
    if (stage == NL - 1) take = 1;
    else {
      const float HH = sm[0] + sm[1] + sm[2] + sm[3];
      const float HO = sm[4] + sm[5] + sm[6] + sm[7];
      const float OO = sm[8] + sm[9] + sm[10] + sm[11];
      const float cosv = HO / (sqrtf(HH) * sqrtf(OO) + 1e-8f);
      take = (cosv >= 0.98f) ? 1 : 0;
    }
    int pos;
    if (take) {
      pos = atomicAdd(&cnts[stage], 1);
      exit_idx[pos] = t;
    } else {
      pos = atomicAdd(&cnts[4 + stage], 1);
      surv_out[pos] = t;
    }
    sif[0] = take; sif[1] = pos;
  }
  __syncthreads();
  if (sif[0]) {
    u16* dst = hexit + (size_t)sif[1] * DIMC;
    ushort4 u;
    u.x = f2bf(o.x); u.y = f2bf(o.y); u.z = f2bf(o.z); u.w = f2bf(o.w);
    ((ushort4*)dst)[tid] = u;
  } else {
    ((float4*)(h + (size_t)t * DIMC))[tid] = o;
    float4 d;
    d.x = o.x - mean; d.y = o.y - mean; d.z = o.z - mean; d.w = o.w - mean;
    float q = d.x * d.x + d.y * d.y + d.z * d.z + d.w * d.w;
#pragma unroll
    for (int off = 32; off; off >>= 1) q += __shfl_down(q, off);
    if (lane == 0) sm[wid] = q;
    __syncthreads();
    const float var = (sm[0] + sm[1] + sm[2] + sm[3]) * (1.0f / DIMC);
    const float rstd = 1.0f / sqrtf(var + 1e-5f);
    float4 gg = ((const float4*)gnx)[tid];
    float4 b2 = ((const float4*)bnx)[tid];
    float o4[4];
    o4[0] = (d.x * rstd * gg.x + b2.x) * 16.f;
    o4[1] = (d.y * rstd * gg.y + b2.y) * 16.f;
    o4[2] = (d.z * rstd * gg.z + b2.z) * 16.f;
    o4[3] = (d.w * rstd * gg.w + b2.w) * 16.f;
    ushort4 u1, u2;
    split16(o4[0], u1.x, u2.x); split16(o4[1], u1.y, u2.y);
    split16(o4[2], u1.z, u2.z); split16(o4[3], u1.w, u2.w);
    const int pos = sif[1];
    ((ushort4*)(hn1 + (size_t)pos * DIMC))[tid] = u1;
    ((ushort4*)(hn2 + (size_t)pos * DIMC))[tid] = u2;
  }
}

// ============ logits: bf16, 256x128 tile, BK=32, dbuf 48KB, 8 waves, 2 blk/CU ============
// counted-vmcnt, rb-fastest XCD-partitioned swizzle (R12-proven; unchanged).
__global__ __launch_bounds__(512, 4) void k_logits(
    const u16* __restrict__ wsb, int offA, int offB,
    const int* __restrict__ pcnt,
    const int* __restrict__ exit_idx,
    float* __restrict__ out)
{
  const int x = blockIdx.x & 7, g = blockIdx.x >> 3;   // grid 4096 = 8 x 512
  const int rb = g & 15;
  const int cb = x * 32 + (g >> 4);                    // 0..255
  if (cb >= VOC / 128) return;                         // 250 real cb
  const int cnt = *pcnt;
  if (rb * 256 >= cnt) return;
  const int n0 = cb * 128;

  __shared__ u16 S[2][12288];          // [A(16 subtiles) | B(8 subtiles)] x 512u16; 48KB
  const int tid = threadIdx.x, w = tid >> 6, l = tid & 63;
  const int lr16 = l & 15, hi = l >> 4;

  int goff[3], loff[3];
#pragma unroll
  for (int q = 0; q < 3; ++q) {
    const int bi = w * 3 + q;          // 24 subtiles: A 0..15, B 16..23
    if (bi < 16) {
      goff[q] = offA + (rb * 256 + bi * 16 + lr16) * DIMC + hi * 8;
      loff[q] = bi * 512;
    } else {
      const int j = bi - 16;
      goff[q] = offB + (n0 + j * 16 + lr16) * DIMC + hi * 8;
      loff[q] = 8192 + j * 512;
    }
  }

  const int wr = w >> 1, wc = w & 1;   // 4M x 2N wave grid, wave tile 64x64
  f32x4 acc[4][4];
#pragma unroll
  for (int mi = 0; mi < 4; ++mi)
#pragma unroll
    for (int ni = 0; ni < 4; ++ni) acc[mi][ni] = (f32x4){0.f, 0.f, 0.f, 0.f};

  auto STAGE = [&](int buf, int kt) {
#pragma unroll
    for (int q = 0; q < 3; ++q)
      gll16(wsb + (size_t)(goff[q] + kt * 32), (void*)&S[buf][loff[q]]);
  };

  STAGE(0, 0);
  STAGE(1, 1);
  const int NT = DIMC / 32;            // 32
  for (int kt = 0; kt < NT; ++kt) {
    const int cur = kt & 1;
    if (kt + 1 < NT) asm volatile("s_waitcnt vmcnt(3)" ::: "memory");
    else             asm volatile("s_waitcnt vmcnt(0)" ::: "memory");
    __builtin_amdgcn_s_barrier();
    bf16x8 aF[4], bF[4];
#pragma unroll
    for (int mi = 0; mi < 4; ++mi)
      aF[mi] = *(const bf16x8*)&S[cur][(wr * 4 + mi) * 512 + l * 8];
#pragma unroll
    for (int ni = 0; ni < 4; ++ni)
      bF[ni] = *(const bf16x8*)&S[cur][8192 + (wc * 4 + ni) * 512 + l * 8];
    __builtin_amdgcn_s_setprio(1);
#pragma unroll
    for (int mi = 0; mi < 4; ++mi)
#pragma unroll
      for (int ni = 0; ni < 4; ++ni)
        acc[mi][ni] = __builtin_amdgcn_mfma_f32_16x16x32_bf16(aF[mi], bF[ni], acc[mi][ni], 0, 0, 0);
    __builtin_amdgcn_s_setprio(0);
    asm volatile("s_waitcnt lgkmcnt(0)" ::: "memory");
    __builtin_amdgcn_s_barrier();
    if (kt + 2 < NT) STAGE(cur, kt + 2);
  }

  const int mvalid = cnt - rb * 256;
#pragma unroll
  for (int mi = 0; mi < 4; ++mi)
#pragma unroll
    for (int r = 0; r < 4; ++r) {
      const int mrow = wr * 64 + mi * 16 + hi * 4 + r;
      if (mrow < mvalid) {
        const int tok = exit_idx[rb * 256 + mrow];
        float* orow = out + (size_t)tok * VOC + n0 + wc * 64 + lr16;
#pragma unroll
        for (int ni = 0; ni < 4; ++ni)
          __builtin_nontemporal_store(acc[mi][ni][r], &orow[ni * 16]);
      }
    }
}

// ---------------- host ----------------
extern "C" void kernel_launch(void* const* d_in, const int* in_sizes, int n_in,
                              void* d_out, int out_size, void* d_ws, size_t ws_size,
                              hipStream_t stream)
{
  const int*   x    = (const int*)d_in[0];
  const float* emb  = (const float*)d_in[1];
  const float* ln_g = (const float*)d_in[2];
  const float* ln_b = (const float*)d_in[3];
  const float* W1   = (const float*)d_in[4];
  const float* b1   = (const float*)d_in[5];
  const float* W2   = (const float*)d_in[6];
  const float* b2   = (const float*)d_in[7];
  const float* Wout = (const float*)d_in[8];
  float* out = (float*)d_out;

  char* p = (char*)d_ws;
  size_t off = 0;
  auto alloc = [&](size_t bytes) -> void* {
    void* r = p + off;
    off += (bytes + 255) & ~(size_t)255;
    return r;
  };
  u16* wsb = (u16*)d_ws;
  float* h    = (float*)alloc((size_t)TK * DIMC * 4);
  float* pbuf = (float*)alloc((size_t)2 * TK * DIMC * 4);   // gemm2 split-K partials
  u16* hn1 = (u16*)alloc((size_t)2 * TK * DIMC * 2);        // dedicated (decide writes it)
  u16* hn2 = hn1 + (size_t)TK * DIMC;
  u16* act1 = (u16*)alloc((size_t)2 * TK * DFFC * 2);       // act1 | act2 contiguous
  u16* act2 = act1 + (size_t)TK * DFFC;
  u16* Woutb = (u16*)alloc((size_t)VOC * DIMC * 2);
  u16* W1all = (u16*)alloc((size_t)NL * 2 * DFFC * DIMC * 2);  // 3 stages x 2 planes
  u16* W2all = (u16*)alloc((size_t)NL * 2 * DIMC * DFFC * 2);
  u16* hexit = (u16*)alloc((size_t)TK * DIMC * 2);
  int* exit_idx = (int*)alloc((size_t)TK * 4);
  int* surv_a   = (int*)alloc((size_t)TK * 4);
  int* surv_b   = (int*)alloc((size_t)TK * 4);
  int* cnts     = (int*)alloc(64 * 4);
  // cnts[0..2]=exit counts; cnts[4..6]=survivor counts; cnts[12]=TK

  const int offHn  = (int)(hn1  - wsb);
  const int offAct = (int)(act1 - wsb);
  const int offWob = (int)(Woutb- wsb);
  const int offW1a = (int)(W1all- wsb);
  const int offW2a = (int)(W2all- wsb);
  const int offHex = (int)(hexit- wsb);
  const int pstrHn  = TK * DIMC;
  const int pstrAct = TK * DFFC;
  const int pstrW   = DFFC * DIMC;

  k_init<<<TK, 256, 0, stream>>>(x, emb, ln_g, ln_b, h, hn1, hn2, surv_a, cnts);
  k_prep<<<8192, 256, 0, stream>>>(W1, W2, W1all, W2all, Wout, Woutb);
  int* surv_in  = surv_a;
  int* surv_out = surv_b;
  for (int i = 0; i < NL; ++i) {
    const int* pM = (i == 0) ? (cnts + 12) : (cnts + 4 + (i - 1));
    k_mlp1<<<256, 512, 0, stream>>>(
        wsb, offHn, pstrHn, offW1a + i * 2 * pstrW, pstrW,
        pM, b1 + (size_t)i * DFFC, act1, act2);
    k_mlp2<<<256, 512, 0, stream>>>(
        wsb, offAct, pstrAct, offW2a + i * 2 * pstrW, pstrW, pM, pbuf);
    const int inx = (i + 1 < NL) ? (i + 1) : i;
    k_decide<<<TK, 256, 0, stream>>>(h, pbuf, b2 + (size_t)i * DIMC,
        surv_in, surv_out, pM, cnts, exit_idx, hexit,
        ln_g + (size_t)inx * DIMC, ln_b + (size_t)inx * DIMC, hn1, hn2, i);
    k_logits<<<4096, 512, 0, stream>>>(wsb, offHex, offWob, cnts + i, exit_idx, out);
    int* tmp = surv_in; surv_in = surv_out; surv_out = tmp;
  }
}